// Round 3
// baseline (175.414 us; speedup 1.0000x reference)
//
#include <hip/hip_runtime.h>
#include <hip/hip_fp16.h>
#include <stdint.h>

// Local-window (5x5) KDE histogram entropy, 256 bins, bandwidth 0.1.
// sigma'((x-b)/0.1) ~ exp(-10|x-b|): only bins {b0-1..b0+2} matter (b0=floor(v)).
// Self-normalized by deposited mass -> truncation error ~1e-4 << 6.3e-2 threshold.
//
// R3: R1 serialized ~100 LDS read-modify-writes per pixel (data-dependent hist
// addresses -> compiler-enforced ~120cy chains; at 1.25 waves/SIMD nothing hides
// them). Deposits are now fire-and-forget non-returning ds_pk_add_f16 via inline
// asm (no result -> no dependency chain; atomicity irrelevant, each thread owns
// its column). Histogram = 128 __half2 bin-pairs x 64 threads, pair-major:
// dword addr = p*64+t -> bank = t%32, independent of data-dependent p ->
// conflict-free zero/scatter/scan. LDS 32 KiB -> 5 blocks/CU.

#define TPB   64
#define NPAIR 128     // 256 bins as 128 __half2 pairs
#define W 96
#define H 96

__device__ __forceinline__ void lds_pk_add_f16(uint32_t byte_off, float lo, float hi)
{
    const __half2 h = __floats2half2_rn(lo, hi);
    const uint32_t data = __builtin_bit_cast(uint32_t, h);
    asm volatile("ds_pk_add_f16 %0, %1" :: "v"(byte_off), "v"(data) : "memory");
}

__global__ __launch_bounds__(TPB) void entropy_kde_kernel(
    const float* __restrict__ x, float* __restrict__ out, int total)
{
    __shared__ __half2 hist[NPAIR * TPB];
    const int t = threadIdx.x;
    const int pix = blockIdx.x * TPB + t;

    // zero own column (each thread owns slots [p][t]; no cross-thread sharing)
    #pragma unroll 8
    for (int p = 0; p < NPAIR; ++p)
        hist[p * TPB + t] = __floats2half2_rn(0.f, 0.f);

    // LDS byte offset of this thread's column base (low 32 bits of generic ptr
    // = LDS offset per gfx9 aperture lowering)
    const uint32_t col0 = (uint32_t)(uintptr_t)(const void*)&hist[t];

    const int xw  = pix % W;
    const int yh  = (pix / W) % H;
    const int img = pix / (W * H);            // fused B*C image index
    const float* base = x + img * (H * W);

    const float C1 = 4.5399929762484854e-05f;   // e^-10
    const float C2 = 2.0611536224385578e-09f;   // e^-20

    float S = 0.f;
    if (pix < total) {
        #pragma unroll
        for (int dy = -2; dy <= 2; ++dy) {
            const int yy = yh + dy;
            if (yy < 0 || yy >= H) continue;
            const float* row = base + yy * W;
            #pragma unroll
            for (int dx = -2; dx <= 2; ++dx) {
                const int xx = xw + dx;
                if (xx < 0 || xx >= W) continue;
                const float v  = row[xx];
                const int   b0 = (int)v;                    // v >= 0
                const float f  = v - (float)b0;             // [0,1)
                // one exp per value: e^{-10(f+j)} = E * e^{-10j}
                const float E   = __expf(-10.f * f);
                const float R   = __builtin_amdgcn_rcpf(E); // e^{+10f}
                const float em1 = (b0 >= 1)   ? E * C1 : 0.f;  // bin b0-1
                const float e1  = R * C1;                      // bin b0+1
                const float e2  = (b0 <= 253) ? R * C2 : 0.f;  // bin b0+2
                // k = e/(1+e)^2 ; em1,e2 <= ~4.5e-5: Taylor e*(1-2e) (err ~6e-9)
                const float r0  = __builtin_amdgcn_rcpf(1.f + E);
                const float r1  = __builtin_amdgcn_rcpf(1.f + e1);
                const float k_m1 = em1 * (1.f - 2.f * em1);
                const float k0   = E  * r0 * r0;
                const float k1   = e1 * r1 * r1;
                const float k2   = e2 * (1.f - 2.f * e2);
                S += k_m1 + k0 + k1 + k2;
                // deposit into 3 aligned pairs q-1,q,q+1 (q = b0>>1), halves by
                // parity: even b0: (.,km1)(k0,k1)(k2,.)  odd: (.,.)(km1,k0)(k1,k2)
                // wrapped pair index: OOB deposits carry 0.0 halves -> harmless
                const int  q   = b0 >> 1;
                const bool odd = (b0 & 1) != 0;
                const uint32_t a0 = col0 + (uint32_t)(((q - 1) & (NPAIR - 1)) * TPB) * 4u;
                const uint32_t a1 = col0 + (uint32_t)(( q      & (NPAIR - 1)) * TPB) * 4u;
                const uint32_t a2 = col0 + (uint32_t)(((q + 1) & (NPAIR - 1)) * TPB) * 4u;
                lds_pk_add_f16(a0, 0.f,             odd ? 0.f : k_m1);
                lds_pk_add_f16(a1, odd ? k_m1 : k0, odd ? k0  : k1);
                lds_pk_add_f16(a2, odd ? k1  : k2,  odd ? k2  : 0.f);
            }
        }
    }

    // drain the pk-adds (same-wave DS ops are in-order; belt-and-braces wait)
    asm volatile("s_waitcnt lgkmcnt(0)" ::: "memory");

    // entropy scan: 128 ds_read_b32, 2 logs per pair
    const float invS = 1.f / (S + 1e-10f);
    float Hacc = 0.f;
    #pragma unroll 8
    for (int p = 0; p < NPAIR; ++p) {
        const float2 a = __half22float2(hist[p * TPB + t]);
        const float q0 = a.x * invS;
        const float q1 = a.y * invS;
        Hacc -= q0 * __logf(q0 + 1e-10f);
        Hacc -= q1 * __logf(q1 + 1e-10f);
    }
    if (pix < total) out[pix] = Hacc;
}

extern "C" void kernel_launch(void* const* d_in, const int* in_sizes, int n_in,
                              void* d_out, int out_size, void* d_ws, size_t ws_size,
                              hipStream_t stream)
{
    const float* x = (const float*)d_in[0];
    float* out = (float*)d_out;
    const int total = in_sizes[0];            // 8*3*96*96 = 221184
    const int blocks = (total + TPB - 1) / TPB;
    entropy_kde_kernel<<<blocks, TPB, 0, stream>>>(x, out, total);
}

// Round 5
// 126.919 us; speedup vs baseline: 1.3821x; 1.3821x over previous
//
#include <hip/hip_runtime.h>
#include <hip/hip_fp16.h>
#include <stdint.h>

// Local-window (5x5) KDE histogram entropy, 256 bins, bandwidth 0.1.
// sigma'((x-b)/0.1) ~ exp(-10|x-b|): only bins b0=floor(v) and b0+1 matter.
// Neglected tail bins carry <= 1.8e-4 of deposited mass (they are e^-10
// RELATIVE to their source value's kept mass) -> entropy error ~2e-3,
// far under the 6.28e-2 threshold. Self-normalized by deposited mass.
//
// R5 == R4 (bench infra failed; no data to revise on):
// 4 lanes cooperate per pixel. Block = 64 threads = 16 pixels,
// lane = s*16 + px (s = 0..3). Histogram = 128 __half2 pairs per pixel,
// layout hist[pair][px] (dword = p*16+px -> bank = 16*(p&1)+px: zero/scan
// 2-way (free), deposits <=4-way). LDS = 8 KiB/block -> 20 blocks/CU =
// 5 waves/SIMD (was 1.25 -> latency finally hides). Lane s handles window
// values j = s, s+4, ... (7/6/6/6 of 25) and scan pairs p = s+4i (32 each).
// Deposits are fire-and-forget ds_pk_add_f16 (a DS *atomic*: intra-wave
// same-address collisions from the 4 cooperating lanes serialize in HW; no
// result -> no RMW chain; no "memory" clobber -> global loads stay hoisted;
// compiler fences order the phases). Cross-lane combine via shfl_xor(16/32).

#define TPB   64
#define PXB   16      // pixels per block
#define NPAIR 128     // 256 bins as 128 __half2 pairs
#define W 96
#define H 96

__device__ __forceinline__ void lds_pk_add_f16(uint32_t byte_off, float lo, float hi)
{
    const __half2 h = __floats2half2_rn(lo, hi);
    const uint32_t data = __builtin_bit_cast(uint32_t, h);
    asm volatile("ds_pk_add_f16 %0, %1" :: "v"(byte_off), "v"(data));
}

__global__ __launch_bounds__(TPB, 5) void entropy_kde_kernel(
    const float* __restrict__ x, float* __restrict__ out, int total)
{
    __shared__ __half2 hist[NPAIR * PXB];
    const int lane = threadIdx.x;
    const int px   = lane & 15;
    const int s    = lane >> 4;

    // zero the 2048 dwords: lane l writes dwords l, l+64, ... -> bank l%32, 2-way (free)
    #pragma unroll 8
    for (int i = 0; i < (NPAIR * PXB) / TPB; ++i)
        ((uint32_t*)hist)[lane + TPB * i] = 0u;
    asm volatile("" ::: "memory");   // compiler fence: zeros stay before deposits

    const int pid  = blockIdx.x * PXB + px;   // PXB | W -> whole block same row/img
    const int xcol = pid % W;
    const int y    = (pid / W) % H;
    const int img  = pid / (W * H);
    const float* base = x + img * (H * W);

    // ---- phase 1: load my 6-7 window values (hoisted, independent) ----
    float vv[7];
    bool  ok[7];
    #pragma unroll
    for (int it = 0; it < 7; ++it) {
        const int jj = s + 4 * it;           // value index 0..24 (jj==25..27 masked)
        const int dy = jj / 5 - 2;
        const int dx = jj % 5 - 2;
        const int yy = y + dy, xx = xcol + dx;
        ok[it] = (jj < 25) && (yy >= 0) && (yy < H) && (xx >= 0) && (xx < W);
        const int yc = min(max(yy, 0), H - 1);
        const int xc = min(max(xx, 0), W - 1);
        vv[it] = base[yc * W + xc];
    }

    // byte offset of pair 0 of my pixel's histogram column
    const uint32_t colbase = (uint32_t)(uintptr_t)(const void*)&hist[px];

    // ---- phase 2: masses + fire-and-forget deposits ----
    float S = 0.f;
    #pragma unroll
    for (int it = 0; it < 7; ++it) {
        const float v  = vv[it];
        const int   b0 = (int)v;                     // v in [0,255) -> b0 in [0,254]
        const float f  = v - (float)b0;              // [0,1)
        const float E  = __expf(-10.f * f);          // e^{-10f}
        const float E2 = __expf(10.f * f - 10.f);    // e^{-10(1-f)}
        const float r0 = __builtin_amdgcn_rcpf(1.f + E);
        const float r1 = __builtin_amdgcn_rcpf(1.f + E2);
        float k0 = E  * r0 * r0;                     // mass at bin b0
        float k1 = E2 * r1 * r1;                     // mass at bin b0+1
        k0 = ok[it] ? k0 : 0.f;
        k1 = ok[it] ? k1 : 0.f;
        S += k0 + k1;
        const int  q   = b0 >> 1;
        const bool odd = (b0 & 1) != 0;
        // even b0: pair q gets (k0,k1), pair q+1 gets (0,0)
        // odd  b0: pair q gets (0,k0),  pair q+1 gets (k1,0)
        const uint32_t a1 = colbase + (uint32_t)(( q      & (NPAIR - 1)) * PXB) * 4u;
        const uint32_t a2 = colbase + (uint32_t)(((q + 1) & (NPAIR - 1)) * PXB) * 4u;
        lds_pk_add_f16(a1, odd ? 0.f : k0, odd ? k0 : k1);
        lds_pk_add_f16(a2, odd ? k1 : 0.f, 0.f);
    }

    // combine S across the 4 lanes of this pixel (lanes px, px+16, px+32, px+48)
    S += __shfl_xor(S, 16);
    S += __shfl_xor(S, 32);
    const float invS = 1.f / (S + 1e-10f);

    // drain deposits (same-wave DS ops are in-order; fence orders scan reads after)
    asm volatile("s_waitcnt lgkmcnt(0)" ::: "memory");

    // ---- phase 3: entropy scan, 32 pairs per lane (p = s+4i -> 2-way banks) ----
    float Hacc = 0.f;
    #pragma unroll 8
    for (int i = 0; i < 32; ++i) {
        const int p = s + 4 * i;
        const float2 a = __half22float2(hist[p * PXB + px]);
        const float q0 = a.x * invS;
        const float q1 = a.y * invS;
        Hacc -= q0 * __logf(q0 + 1e-10f);   // untouched bins: exactly 0 -> term 0
        Hacc -= q1 * __logf(q1 + 1e-10f);
    }
    Hacc += __shfl_xor(Hacc, 16);
    Hacc += __shfl_xor(Hacc, 32);
    if (s == 0 && pid < total) out[pid] = Hacc;
}

extern "C" void kernel_launch(void* const* d_in, const int* in_sizes, int n_in,
                              void* d_out, int out_size, void* d_ws, size_t ws_size,
                              hipStream_t stream)
{
    const float* x = (const float*)d_in[0];
    float* out = (float*)d_out;
    const int total  = in_sizes[0];                  // 8*3*96*96 = 221184
    const int blocks = (total + PXB - 1) / PXB;      // 13824
    entropy_kde_kernel<<<blocks, TPB, 0, stream>>>(x, out, total);
}

// Round 6
// 120.369 us; speedup vs baseline: 1.4573x; 1.0544x over previous
//
#include <hip/hip_runtime.h>
#include <hip/hip_fp16.h>
#include <stdint.h>

// Local-window (5x5) KDE histogram entropy, 256 bins, bandwidth 0.1.
// sigma'((x-b)/0.1) ~ exp(-10|x-b|): only bins b0=floor(v), b0+1 matter
// (truncation error ~2e-3 entropy, threshold is 6.28e-2; validated R5).
//
// R6: NO entropy scan. H = ln S - T/S with T = sum_b m_b ln m_b maintained
// incrementally: ds_pk_add_rtn_f16 returns the bin's old mass a, so each
// deposit contributes (a+k)ln(a+k) - a ln a (telescopes under any atomic
// order; collisions exact; masked k=0 deposits cancel identically). This
// removes 64 logs + 32 ds_reads per lane (the R5 scan was ~half the issue
// work, 80% of logs on zero-mass bins). TPB=128 (2 waves, 32 px) for
// occupancy: 16 KiB LDS -> 10 blocks/CU = 20 waves/CU. Wave-private pixel
// rows + wave-local zeroing -> no __syncthreads anywhere.
// Layout hist[px][pair]: bank = pair%32, data-dependent ~uniform -> ~2-way.

#define TPB   128
#define PXB   32      // pixels per block (16 per wave)
#define W 96
#define H 96

__global__ __launch_bounds__(TPB, 5) void entropy_kde_kernel(
    const float* __restrict__ x, float* __restrict__ out, int total)
{
    __shared__ __half2 hist[PXB * 128];    // 128 __half2 pairs (256 bins) per pixel
    const int lane = threadIdx.x;          // 0..127
    const int wv   = lane >> 6;            // wave 0/1
    const int wl   = lane & 63;            // lane within wave
    const int px_l = wl & 15;              // pixel within wave
    const int s    = (wl >> 4) & 3;        // 4 cooperating lanes per pixel
    const int px   = wv * 16 + px_l;       // 0..31

    // zero own wave's pixel rows (dwords [wv*2048, wv*2048+2047]) -> wave-local,
    // DS pipe is in-order per wave, so no barrier needed before deposits.
    {
        uint32_t* hz = (uint32_t*)hist + wv * 2048;
        #pragma unroll
        for (int i = 0; i < 32; ++i)
            hz[wl + 64 * i] = 0u;
    }
    // memory-clobber fence: (a) zero stores can't sink below, (b) they are
    // observable -> not DCE'd even though no visible C++ read of hist follows.
    asm volatile("" ::: "memory");

    const int pid  = blockIdx.x * PXB + px;   // PXB | W: block spans one row segment
    const int xcol = pid % W;
    const int y    = (pid / W) % H;
    const int img  = pid / (W * H);
    const float* base = x + img * (H * W);

    // ---- phase 1: load my 6-7 window values into registers ----
    float vv[7]; bool ok[7];
    #pragma unroll
    for (int it = 0; it < 7; ++it) {
        const int jj = s + 4 * it;            // 0..24 live, 25..27 masked
        const int dy = jj / 5 - 2, dx = jj % 5 - 2;
        const int yy = y + dy, xx = xcol + dx;
        ok[it] = (jj < 25) && (yy >= 0) && (yy < H) && (xx >= 0) && (xx < W);
        vv[it] = base[min(max(yy, 0), H - 1) * W + min(max(xx, 0), W - 1)];
    }

    const uint32_t rowbase = (uint32_t)(uintptr_t)(const void*)&hist[px * 128];

    // ---- phase 2: masses + returning deposits (all issued before one wait) ----
    float k0c[7], k1c[7]; uint32_t r1[7], r2[7]; int b0a[7];
    float S = 0.f;
    #pragma unroll
    for (int it = 0; it < 7; ++it) {
        const float v  = vv[it];
        const int   b0 = (int)v;                   // v in [0,255) -> b0 in [0,254]
        const float f  = v - (float)b0;            // [0,1)
        const float E  = __expf(-10.f * f);        // e^{-10f}
        const float E2 = __expf(10.f * f - 10.f);  // e^{-10(1-f)}
        const float r0 = __builtin_amdgcn_rcpf(1.f + E);
        const float rb = __builtin_amdgcn_rcpf(1.f + E2);
        float k0 = E  * r0 * r0;                   // mass at bin b0
        float k1 = E2 * rb * rb;                   // mass at bin b0+1
        k0 = ok[it] ? k0 : 0.f;
        k1 = ok[it] ? k1 : 0.f;
        // round to fp16 ONCE; use the rounded values in bins, S and T (consistent)
        const __half2 hk = __floats2half2_rn(k0, k1);
        const float2  kc = __half22float2(hk);
        k0c[it] = kc.x; k1c[it] = kc.y;
        S += kc.x + kc.y;
        b0a[it] = b0;
        const int  q   = b0 >> 1;
        const bool odd = (b0 & 1) != 0;
        // even b0: pair q += (k0,k1), pair q+1 += (0,0)
        // odd  b0: pair q += (0,k0),  pair q+1 += (k1,0)
        const __half2 d1 = __floats2half2_rn(odd ? 0.f : kc.x, odd ? kc.x : kc.y);
        const __half2 d2 = __floats2half2_rn(odd ? kc.y : 0.f, 0.f);
        const uint32_t a1 = rowbase + (uint32_t)(q * 4);
        const uint32_t a2 = rowbase + (uint32_t)(((q + 1) & 127) * 4); // b0=254 wraps w/ zero data
        asm volatile("ds_pk_add_rtn_f16 %0, %1, %2"
                     : "=v"(r1[it]) : "v"(a1), "v"(__builtin_bit_cast(uint32_t, d1)));
        asm volatile("ds_pk_add_rtn_f16 %0, %1, %2"
                     : "=v"(r2[it]) : "v"(a2), "v"(__builtin_bit_cast(uint32_t, d2)));
    }

    // one drain for all 14 atomics; tie every result register through the asm so
    // no use can be scheduled before the wait (rule-#18 hoist hazard), plus a
    // hard scheduler fence.
    asm volatile("s_waitcnt lgkmcnt(0)"
                 : "+v"(r1[0]), "+v"(r1[1]), "+v"(r1[2]), "+v"(r1[3]),
                   "+v"(r1[4]), "+v"(r1[5]), "+v"(r1[6]),
                   "+v"(r2[0]), "+v"(r2[1]), "+v"(r2[2]), "+v"(r2[3]),
                   "+v"(r2[4]), "+v"(r2[5]), "+v"(r2[6]));
    __builtin_amdgcn_sched_barrier(0);

    // ---- phase 3: T += (a+k)ln(a+k) - a ln a per deposited bin ----
    float T = 0.f;
    #pragma unroll
    for (int it = 0; it < 7; ++it) {
        const bool odd = (b0a[it] & 1) != 0;
        const float2 h1 = __half22float2(__builtin_bit_cast(__half2, r1[it]));
        const float2 h2 = __half22float2(__builtin_bit_cast(__half2, r2[it]));
        const float a0 = odd ? h1.y : h1.x;   // old mass at bin b0
        const float a1 = odd ? h2.x : h1.y;   // old mass at bin b0+1
        const float z0 = a0 + k0c[it];
        const float z1 = a1 + k1c[it];
        // g(z) = z*ln(z+eps); g(0)=0, and k=0 (masked) cancels exactly.
        T += z0 * __logf(z0 + 1e-10f) - a0 * __logf(a0 + 1e-10f)
           + z1 * __logf(z1 + 1e-10f) - a1 * __logf(a1 + 1e-10f);
    }

    // combine across the 4 lanes of this pixel (xor 16 / 32 stays in-wave)
    S += __shfl_xor(S, 16);  S += __shfl_xor(S, 32);
    T += __shfl_xor(T, 16);  T += __shfl_xor(T, 32);

    if (s == 0 && pid < total) {
        const float Sp = S + 1e-10f;
        out[pid] = __logf(Sp) - T / Sp;
    }
}

extern "C" void kernel_launch(void* const* d_in, const int* in_sizes, int n_in,
                              void* d_out, int out_size, void* d_ws, size_t ws_size,
                              hipStream_t stream)
{
    const float* x = (const float*)d_in[0];
    float* out = (float*)d_out;
    const int total  = in_sizes[0];                  // 8*3*96*96 = 221184
    const int blocks = (total + PXB - 1) / PXB;      // 6912
    entropy_kde_kernel<<<blocks, TPB, 0, stream>>>(x, out, total);
}

// Round 7
// 82.037 us; speedup vs baseline: 2.1382x; 1.4672x over previous
//
#include <hip/hip_runtime.h>
#include <stdint.h>

// Local-window (5x5) KDE histogram entropy, 256 bins, bandwidth 0.1.
// sigma'((x-b)/0.1) ~ exp(-10|x-b|): only bins b0=floor(v), b0+1 carry mass
// (dropped bins are <=1.8e-4 relative; validated across R5/R6, error ~2e-3
// vs threshold 6.28e-2). Self-normalized by deposited mass.
//
// R7: NO LDS, NO atomics. R5/R6 evidence: per-CU DS unit serialized on fp16
// LDS atomics (~3cy/lane RMW) -> 72us floor regardless of VALU/trans cuts.
// Merging only matters WITHIN a pixel's 25 values, and each value touches
// <=2 adjacent bins -> O(25^2) register-resident prefix-merge, 1 pixel/lane:
//   for value i, P0/P1 = sum of earlier values' masses landing in bins
//   b0_i / b0_i+1 (bin distance d in {-1,0,1} selects k0/k1), then
//   T += (P+k)ln(P+k) - P ln P   (telescopes exactly to sum_b M_b ln M_b)
//   H = ln S - T/S.
// All arrays fully unrolled -> static register indices (rule #20). f32
// throughout -> absmax drops to pure truncation error.

#define W 96
#define H 96
#define TPB 256

__global__ __launch_bounds__(TPB) void entropy_kde_kernel(
    const float* __restrict__ x, float* __restrict__ out, int total)
{
    const int pid = blockIdx.x * TPB + threadIdx.x;
    if (pid >= total) return;                 // grid is exact; guard is free

    const int xcol = pid % W;
    const int y    = (pid / W) % H;
    const int img  = pid / (W * H);
    const float* __restrict__ base = x + img * (H * W);

    int   b0a[25];
    float k0a[25], k1a[25];
    float S = 0.f, T = 0.f;

    #pragma unroll
    for (int i = 0; i < 25; ++i) {
        const int dy = i / 5 - 2, dx = i % 5 - 2;      // constants after unroll
        const int yy = y + dy,    xx = xcol + dx;
        const bool ok = (yy >= 0) & (yy < H) & (xx >= 0) & (xx < W);
        const float v = base[min(max(yy, 0), H - 1) * W + min(max(xx, 0), W - 1)];

        const int   b0 = (int)v;                       // v in [0,255) -> [0,254]
        const float f  = v - (float)b0;                // [0,1)
        const float E  = __expf(-10.f * f);            // e^{-10f}
        const float E2 = __expf(10.f * f - 10.f);      // e^{-10(1-f)}
        const float r0 = __builtin_amdgcn_rcpf(1.f + E);
        const float r1 = __builtin_amdgcn_rcpf(1.f + E2);
        const float k0 = ok ? E  * r0 * r0 : 0.f;      // mass at bin b0
        const float k1 = ok ? E2 * r1 * r1 : 0.f;      // mass at bin b0+1

        // prefix masses already deposited by earlier values into my two bins
        float P0 = 0.f, P1 = 0.f;
        #pragma unroll
        for (int j = 0; j < i; ++j) {
            const int d = b0 - b0a[j];                 // my bin A = b0
            // j's k0 sits at b0a[j] (d==0 -> A, d==-1 -> B=b0+1)
            // j's k1 sits at b0a[j]+1 (d==1 -> A, d==0 -> B)
            P0 += (d == 0) ? k0a[j] : ((d ==  1) ? k1a[j] : 0.f);
            P1 += (d == 0) ? k1a[j] : ((d == -1) ? k0a[j] : 0.f);
        }

        // telescoping entropy-numerator update (exact under this fixed order;
        // k==0 (masked) cancels identically since z==P)
        const float z0 = P0 + k0, z1 = P1 + k1;
        T += z0 * __logf(z0 + 1e-10f) - P0 * __logf(P0 + 1e-10f)
           + z1 * __logf(z1 + 1e-10f) - P1 * __logf(P1 + 1e-10f);
        S += k0 + k1;

        b0a[i] = b0; k0a[i] = k0; k1a[i] = k1;
    }

    const float Sp = S + 1e-10f;
    out[pid] = __logf(Sp) - T / Sp;
}

extern "C" void kernel_launch(void* const* d_in, const int* in_sizes, int n_in,
                              void* d_out, int out_size, void* d_ws, size_t ws_size,
                              hipStream_t stream)
{
    const float* x = (const float*)d_in[0];
    float* out = (float*)d_out;
    const int total  = in_sizes[0];                    // 8*3*96*96 = 221184
    const int blocks = (total + TPB - 1) / TPB;        // 864
    entropy_kde_kernel<<<blocks, TPB, 0, stream>>>(x, out, total);
}